// Round 15
// baseline (212.861 us; speedup 1.0000x reference)
//
#include <hip/hip_runtime.h>
#include <math.h>

typedef _Float16 f16;
typedef f16 f16x8 __attribute__((ext_vector_type(8)));
typedef float f32x16 __attribute__((ext_vector_type(16)));

static constexpr int Bn = 16;
static constexpr int Kn = 4096;
static constexpr int NPTS = Bn * Kn;    // 65536
static constexpr int MGRID = 512;       // qg8(16) x b(16) x dir(2)
static constexpr int NPSUM = 1024;      // old 1024-slot psum layout
static constexpr float WBIG = 49152.0f; // exact in fp16
static constexpr float QMIN0 = 3e37f;

// Round-15: R14 base (best, 27.7) + ONE change: the A-side raw points are
// staged into LDS (SoA x/y/z/w, 64 KB) once per block, removing the
// in-loop global load (mask + 3 floats, ~200-300 cyc L2/L3) from the
// per-t serial chain. Arithmetic: fused ~20-21 us vs ~12.5 us of
// serialized MFMA-issue + VALU -> ~8 us residual = latency exposure; the
// only in-loop latency left is this VMEM chain (R6's prefetch test of the
// same mechanism was invalidated by spill). In-loop A-reads become 4
// conflict-free ds_read_b32 (lanes 0-31 stride-4; upper half broadcast,
// free) with fine-grained lgkmcnt. Mask is folded into w at staging
// (valid: w=|p|^2 via the identical fmaf -> bit-identical build inputs;
// invalid: xyz=0, w=-1 sentinel). Static LDS 72 KB (gfx950 allows >64 KB
// static; guide's 8-phase GEMM uses 128 KB) -> 2 blocks/CU, occupancy
// unchanged. Everything else R14 verbatim -> bitwise-identical output.
// Tripwires: regression = staging cost; LDS_Block_Size ~73.7 KB expected.
__global__ __launch_bounds__(256, 2) void chamfer_fused_kernel(
        const float* __restrict__ pred, const float* __restrict__ target,
        const int* __restrict__ mask,
        float* __restrict__ psum, unsigned int* __restrict__ cnt4) {
    int bid = blockIdx.x;
    int lin = (bid & 7) * 64 + (bid >> 3);    // XCD-contiguous logical id
    int qg8 = lin & 15; lin >>= 4;            // qg8(16) fastest, b(16), dir(2)
    int b   = lin & 15; lin >>= 4;
    int dir = lin;                            // 0: queries=pred, refs=target
    int j0 = dir * 512 + b * 32 + qg8 * 2;    // old logical psum slots
    int j1 = j0 + 1;

    const float* __restrict__ Araw = dir ? pred : target;  // refs
    const float* __restrict__ Braw = dir ? target : pred;  // queries

    int tid = threadIdx.x;
    int w = tid >> 6, l = tid & 63;
    int r = l & 31, g = l >> 5;

    __shared__ float stx[4096], sty[4096], stz[4096], stw[4096];
    __shared__ float comb[4][8][64];

    // ---- stage A-side points (SoA; mask folded into w) ----
    #pragma unroll
    for (int k = 0; k < 16; ++k) {
        int p = tid + 256 * k;                 // lane-stride-1 LDS writes
        int idx = b * 4096 + p;
        bool v = mask[idx] != 0;
        float x = Araw[idx * 3 + 0], y = Araw[idx * 3 + 1], z = Araw[idx * 3 + 2];
        if (!v) { x = 0.0f; y = 0.0f; z = 0.0f; }
        stx[p] = x; sty[p] = y; stz[p] = z;
        stw[p] = v ? fmaf(x, x, fmaf(y, y, z * z)) : -1.0f;
    }

    // opaque zero C-operand: runtime value IS 0, provenance hidden.
    float zf;
    asm volatile("v_mov_b32 %0, 0" : "=v"(zf));
    f32x16 cz;
    #pragma unroll
    for (int i = 0; i < 16; ++i) cz[i] = zf;

    const f16 one = (f16)1.0f, zero = (f16)0.0f;

    // ---- B fragments for this block's 8 query tiles (unchanged) ----
    f16x8 bq[8];
    unsigned int bcnt[8];
    #pragma unroll
    for (int qt = 0; qt < 8; ++qt) {
        int idx = b * 4096 + (qg8 * 8 + qt) * 32 + r;
        bool valid = mask[idx] != 0;
        float x = Braw[idx * 3 + 0], y = Braw[idx * 3 + 1], z = Braw[idx * 3 + 2];
        if (!valid) { x = 0.0f; y = 0.0f; z = 0.0f; }
        float wv = fmaf(x, x, fmaf(y, y, z * z));
        f16 xh = (f16)x, yh = (f16)y, zh = (f16)z;
        f16 xl = (f16)(x - (float)xh), yl = (f16)(y - (float)yh), zl = (f16)(z - (float)zh);
        f16 whB, wlB;
        if (valid) { f16 wh = (f16)wv; whB = wh; wlB = (f16)(wv - (float)wh); }
        else       { whB = (f16)(-WBIG); wlB = zero; }
        f16x8 blo = {xh, xl, xh, yh, yl, yh, zh, zl};
        f16x8 bhi = {zh, one, one, whB, wlB, zero, zero, zero};
        bq[qt] = g ? bhi : blo;
        // lanes r and r+32 hold the same point -> popcll is 2x the count
        unsigned long long mb = __ballot(valid);
        bcnt[qt] = (unsigned int)__popcll(mb) >> 1;
    }
    // dir=0 blocks own cnt4 slots b*64 + qg8*4 + m (same values as before)
    if (dir == 0 && w == 0 && l == 0) {
        #pragma unroll
        for (int m = 0; m < 4; ++m)
            cnt4[b * 64 + qg8 * 4 + m] = bcnt[2 * m] + bcnt[2 * m + 1];
    }

    __syncthreads();   // staged A-points visible

    float qA[8], qB[8];
    #pragma unroll
    for (int qt = 0; qt < 8; ++qt) { qA[qt] = QMIN0; qB[qt] = QMIN0; }

    // wave w covers ref tiles rt = w + 4t, t = 0..31 (exact R14 order).
    #pragma unroll 4
    for (int t = 0; t < 32; ++t) {
        int pt = (w + 4 * t) * 32 + r;
        float x = stx[pt], y = sty[pt], z = stz[pt], wv = stw[pt];
        bool valid = wv >= 0.0f;
        // A slots (bit-identical to R14's build: staged x/y/z/wv are the
        // same post-mask values and the same fmaf result)
        f16 xh = (f16)x, yh = (f16)y, zh = (f16)z;
        f16 xl = (f16)(x - (float)xh), yl = (f16)(y - (float)yh), zl = (f16)(z - (float)zh);
        f16 m2xh = (f16)(-2.0f * (float)xh), m2xl = (f16)(-2.0f * (float)xl);
        f16 m2yh = (f16)(-2.0f * (float)yh), m2yl = (f16)(-2.0f * (float)yl);
        f16 m2zh = (f16)(-2.0f * (float)zh), m2zl = (f16)(-2.0f * (float)zl);
        f16 whA, wlA;
        if (valid) { f16 wh = (f16)wv; whA = wh; wlA = (f16)(wv - (float)wh); }
        else       { whA = (f16)WBIG; wlA = zero; }
        f16x8 alo = {m2xh, m2xh, m2xl, m2yh, m2yh, m2yl, m2zh, m2zh};
        f16x8 ahi = {m2zl, whA, wlA, one, one, zero, zero, zero};
        f16x8 a = g ? ahi : alo;

        #pragma unroll
        for (int qt = 0; qt < 8; ++qt) {
            f32x16 d = __builtin_amdgcn_mfma_f32_32x32x16_f16(a, bq[qt], cz, 0, 0, 0);
            asm volatile("" : "+v"(d));   // pin MFMA dst to VGPRs
            #pragma unroll
            for (int i = 0; i < 4; ++i) {
                qA[qt] = fminf(fminf(qA[qt], d[4 * i + 0]), d[4 * i + 1]);  // -> v_min3
                qB[qt] = fminf(fminf(qB[qt], d[4 * i + 2]), d[4 * i + 3]);  // -> v_min3
            }
        }
    }

    #pragma unroll
    for (int qt = 0; qt < 8; ++qt) comb[w][qt][l] = fminf(qA[qt], qB[qt]);
    __syncthreads();

    // Two independent reductions, each the EXACT old-block computation.
    float c0 = 0.0f, c1 = 0.0f;
    if (tid < 128) {
        int qt = tid >> 5, c = tid & 31;
        float m0 = QMIN0, m1 = QMIN0;
        #pragma unroll
        for (int ww = 0; ww < 4; ++ww)
            #pragma unroll
            for (int h = 0; h < 2; ++h) {
                m0 = fminf(m0, comb[ww][qt][h * 32 + c]);
                m1 = fminf(m1, comb[ww][qt + 4][h * 32 + c]);
            }
        // m < -1e4 marks an invalid query (w_q = -WBIG); contributes 0
        c0 = (m0 < -1e4f) ? 0.0f : sqrtf(fmaxf(m0, 1e-12f));
        c1 = (m1 < -1e4f) ? 0.0f : sqrtf(fmaxf(m1, 1e-12f));
    }
    for (int off = 32; off; off >>= 1) {
        c0 += __shfl_down(c0, off, 64);
        c1 += __shfl_down(c1, off, 64);
    }
    __shared__ float ps0[4], ps1[4];
    if ((tid & 63) == 0) { ps0[tid >> 6] = c0; ps1[tid >> 6] = c1; }
    __syncthreads();
    if (tid == 0) {
        psum[j0] = ps0[0] + ps0[1] + ps0[2] + ps0[3];
        psum[j1] = ps1[0] + ps1[1] + ps1[2] + ps1[3];
    }
}

__global__ __launch_bounds__(256) void final_kernel(
        const unsigned int* __restrict__ cnt4, const float* __restrict__ psum,
        float* __restrict__ out) {
    int t = threadIdx.x;
    unsigned int c = 0;
    float s = 0.0f;
    #pragma unroll
    for (int i = 0; i < 4; ++i) {
        c += cnt4[t + 256 * i];
        s += psum[t + 256 * i];
    }
    for (int off = 32; off; off >>= 1) {
        c += __shfl_down(c, off, 64);
        s += __shfl_down(s, off, 64);
    }
    __shared__ unsigned int cs[4];
    __shared__ float ss[4];
    if ((t & 63) == 0) { cs[t >> 6] = c; ss[t >> 6] = s; }
    __syncthreads();
    if (t == 0) {
        unsigned int C = cs[0] + cs[1] + cs[2] + cs[3];
        float S = ss[0] + ss[1] + ss[2] + ss[3];
        out[0] = S * 0.5f / ((float)C + 1e-8f);
    }
}

extern "C" void kernel_launch(void* const* d_in, const int* in_sizes, int n_in,
                              void* d_out, int out_size, void* d_ws, size_t ws_size,
                              hipStream_t stream) {
    const float* pred = (const float*)d_in[0];
    const float* target = (const float*)d_in[1];
    const int* mask = (const int*)d_in[2];
    float* out = (float*)d_out;

    // ws: [psum 4K | cnt4 4K]
    char* ws = (char*)d_ws;
    float* psum = (float*)ws;
    unsigned int* cnt4 = (unsigned int*)(ws + NPSUM * sizeof(float));

    chamfer_fused_kernel<<<MGRID, 256, 0, stream>>>(
        pred, target, mask, psum, cnt4);
    final_kernel<<<1, 256, 0, stream>>>(cnt4, psum, out);
}

// Round 16
// 31.140 us; speedup vs baseline: 6.8356x; 6.8356x over previous
//
#include <hip/hip_runtime.h>
#include <math.h>

typedef _Float16 f16;
typedef f16 f16x8 __attribute__((ext_vector_type(8)));
typedef float f32x16 __attribute__((ext_vector_type(16)));

static constexpr int Bn = 16;
static constexpr int Kn = 4096;
static constexpr int NPTS = Bn * Kn;    // 65536
static constexpr int MGRID = 1024;      // qg(32) x b(16) x dir(2)
static constexpr int NPSUM = 1024;
static constexpr float WBIG = 49152.0f; // exact in fp16
static constexpr float QMIN0 = 3e37f;

// Round-16: R14's fused loop VERBATIM but qt=4 / 1024 blocks /
// __launch_bounds__(256,4). Rationale: R15's LDS-staging probe was
// invalidated by spill (VGPR pinned 128, WRITE 26 MB). The one axis never
// validly probed in the FUSED regime is blocks-per-CU: R3's null was
// fragment-regime (narrow blocks doubled the 128 KB/block fragment
// stream); in the fused regime A-side reads are raw L2-resident points
// (64 KB/block of a 1.8 MB input), so splitting blocks duplicates only
// cache hits. 1024 blocks = 4 blocks/CU = 4 waves/SIMD (2x R14),
// breaking the 2-wave build->MFMA->drain convoy. qt=4 halves register
// need (~75-90; R5's qt=4 loop compiled at 40) << 128 cap -> no clamp.
// Bitwise: original 1024-block decomposition restored -> psum/cnt4/
// final_kernel are the R5-proven byte-identical forms; per-qt bq/qA/qB
// chains identical to R14's (min regrouping exact, same per-qt order).
__global__ __launch_bounds__(256, 4) void chamfer_fused_kernel(
        const float* __restrict__ pred, const float* __restrict__ target,
        const int* __restrict__ mask,
        float* __restrict__ psum, unsigned int* __restrict__ cnt4) {
    int bid = blockIdx.x;
    int lin = (bid & 7) * 128 + (bid >> 3);   // XCD-contiguous logical id
    int pidx = lin;                           // psum slot = logical id
    int qg = lin & 31; lin >>= 5;             // qg(32) fastest, b(16), dir(2)
    int b  = lin & 15; lin >>= 4;
    int dir = lin;                            // 0: queries=pred, refs=target

    const float* __restrict__ Araw = dir ? pred : target;  // refs
    const float* __restrict__ Braw = dir ? target : pred;  // queries

    int tid = threadIdx.x;
    int w = tid >> 6, l = tid & 63;
    int r = l & 31, g = l >> 5;

    __shared__ float comb[4][4][64];

    // opaque zero C-operand: runtime value IS 0, provenance hidden.
    float zf;
    asm volatile("v_mov_b32 %0, 0" : "=v"(zf));
    f32x16 cz;
    #pragma unroll
    for (int i = 0; i < 16; ++i) cz[i] = zf;

    const f16 one = (f16)1.0f, zero = (f16)0.0f;

    // ---- B fragments for this block's 4 query tiles (same bit-values as
    // old prep's B slots: B = {xh,xl,xh,yh,yl,yh,zh,zl | zh,1,1,whB,wlB,0,0,0})
    f16x8 bq[4];
    unsigned int bcnt[4];
    #pragma unroll
    for (int qt = 0; qt < 4; ++qt) {
        int idx = b * 4096 + (qg * 4 + qt) * 32 + r;
        bool valid = mask[idx] != 0;
        float x = Braw[idx * 3 + 0], y = Braw[idx * 3 + 1], z = Braw[idx * 3 + 2];
        if (!valid) { x = 0.0f; y = 0.0f; z = 0.0f; }
        float wv = fmaf(x, x, fmaf(y, y, z * z));
        f16 xh = (f16)x, yh = (f16)y, zh = (f16)z;
        f16 xl = (f16)(x - (float)xh), yl = (f16)(y - (float)yh), zl = (f16)(z - (float)zh);
        f16 whB, wlB;
        if (valid) { f16 wh = (f16)wv; whB = wh; wlB = (f16)(wv - (float)wh); }
        else       { whB = (f16)(-WBIG); wlB = zero; }
        f16x8 blo = {xh, xl, xh, yh, yl, yh, zh, zl};
        f16x8 bhi = {zh, one, one, whB, wlB, zero, zero, zero};
        bq[qt] = g ? bhi : blo;
        // lanes r and r+32 hold the same point -> popcll is 2x the count
        unsigned long long mb = __ballot(valid);
        bcnt[qt] = (unsigned int)__popcll(mb) >> 1;
    }
    // dir=0 blocks own cnt4 slots b*64 + qg*2 + m (64 consecutive points
    // each = qt pair (2m,2m+1)) — same values as old prep's ballots.
    if (dir == 0 && w == 0 && l == 0) {
        #pragma unroll
        for (int m = 0; m < 2; ++m)
            cnt4[b * 64 + qg * 2 + m] = bcnt[2 * m] + bcnt[2 * m + 1];
    }

    float qA[4], qB[4];
    #pragma unroll
    for (int qt = 0; qt < 4; ++qt) { qA[qt] = QMIN0; qB[qt] = QMIN0; }

    // wave w covers ref tiles rt = w + 4t, t = 0..31 (exact R14 order).
    #pragma unroll 4
    for (int t = 0; t < 32; ++t) {
        int idxA = b * 4096 + (w + 4 * t) * 32 + r;
        bool valid = mask[idxA] != 0;
        float x = Araw[idxA * 3 + 0], y = Araw[idxA * 3 + 1], z = Araw[idxA * 3 + 2];
        if (!valid) { x = 0.0f; y = 0.0f; z = 0.0f; }
        // A slots (bit-identical to old prep):
        // A = {m2xh,m2xh,m2xl,m2yh,m2yh,m2yl,m2zh,m2zh | m2zl,whA,wlA,1,1,0,0,0}
        float wv = fmaf(x, x, fmaf(y, y, z * z));
        f16 xh = (f16)x, yh = (f16)y, zh = (f16)z;
        f16 xl = (f16)(x - (float)xh), yl = (f16)(y - (float)yh), zl = (f16)(z - (float)zh);
        f16 m2xh = (f16)(-2.0f * (float)xh), m2xl = (f16)(-2.0f * (float)xl);
        f16 m2yh = (f16)(-2.0f * (float)yh), m2yl = (f16)(-2.0f * (float)yl);
        f16 m2zh = (f16)(-2.0f * (float)zh), m2zl = (f16)(-2.0f * (float)zl);
        f16 whA, wlA;
        if (valid) { f16 wh = (f16)wv; whA = wh; wlA = (f16)(wv - (float)wh); }
        else       { whA = (f16)WBIG; wlA = zero; }
        f16x8 alo = {m2xh, m2xh, m2xl, m2yh, m2yh, m2yl, m2zh, m2zh};
        f16x8 ahi = {m2zl, whA, wlA, one, one, zero, zero, zero};
        f16x8 a = g ? ahi : alo;

        #pragma unroll
        for (int qt = 0; qt < 4; ++qt) {
            f32x16 d = __builtin_amdgcn_mfma_f32_32x32x16_f16(a, bq[qt], cz, 0, 0, 0);
            asm volatile("" : "+v"(d));   // pin MFMA dst to VGPRs
            #pragma unroll
            for (int i = 0; i < 4; ++i) {
                qA[qt] = fminf(fminf(qA[qt], d[4 * i + 0]), d[4 * i + 1]);  // -> v_min3
                qB[qt] = fminf(fminf(qB[qt], d[4 * i + 2]), d[4 * i + 3]);  // -> v_min3
            }
        }
    }

    #pragma unroll
    for (int qt = 0; qt < 4; ++qt) comb[w][qt][l] = fminf(qA[qt], qB[qt]);
    __syncthreads();

    // EXACT old-block reduction (R5-proven order).
    float contrib = 0.0f;
    if (tid < 128) {
        int qt = tid >> 5, c = tid & 31;
        float m = QMIN0;
        #pragma unroll
        for (int ww = 0; ww < 4; ++ww)
            #pragma unroll
            for (int h = 0; h < 2; ++h)
                m = fminf(m, comb[ww][qt][h * 32 + c]);
        // m < -1e4 marks an invalid query (w_q = -WBIG); contributes 0
        contrib = (m < -1e4f) ? 0.0f : sqrtf(fmaxf(m, 1e-12f));
    }
    for (int off = 32; off; off >>= 1)
        contrib += __shfl_down(contrib, off, 64);
    __shared__ float ps[4];
    if ((tid & 63) == 0) ps[tid >> 6] = contrib;
    __syncthreads();
    if (tid == 0)
        psum[pidx] = ps[0] + ps[1] + ps[2] + ps[3];
}

__global__ __launch_bounds__(256) void final_kernel(
        const unsigned int* __restrict__ cnt4, const float* __restrict__ psum,
        float* __restrict__ out) {
    int t = threadIdx.x;
    unsigned int c = 0;
    float s = 0.0f;
    #pragma unroll
    for (int i = 0; i < 4; ++i) {
        c += cnt4[t + 256 * i];
        s += psum[t + 256 * i];
    }
    for (int off = 32; off; off >>= 1) {
        c += __shfl_down(c, off, 64);
        s += __shfl_down(s, off, 64);
    }
    __shared__ unsigned int cs[4];
    __shared__ float ss[4];
    if ((t & 63) == 0) { cs[t >> 6] = c; ss[t >> 6] = s; }
    __syncthreads();
    if (t == 0) {
        unsigned int C = cs[0] + cs[1] + cs[2] + cs[3];
        float S = ss[0] + ss[1] + ss[2] + ss[3];
        out[0] = S * 0.5f / ((float)C + 1e-8f);
    }
}

extern "C" void kernel_launch(void* const* d_in, const int* in_sizes, int n_in,
                              void* d_out, int out_size, void* d_ws, size_t ws_size,
                              hipStream_t stream) {
    const float* pred = (const float*)d_in[0];
    const float* target = (const float*)d_in[1];
    const int* mask = (const int*)d_in[2];
    float* out = (float*)d_out;

    // ws: [psum 4K | cnt4 4K]
    char* ws = (char*)d_ws;
    float* psum = (float*)ws;
    unsigned int* cnt4 = (unsigned int*)(ws + NPSUM * sizeof(float));

    chamfer_fused_kernel<<<MGRID, 256, 0, stream>>>(
        pred, target, mask, psum, cnt4);
    final_kernel<<<1, 256, 0, stream>>>(cnt4, psum, out);
}

// Round 17
// 27.755 us; speedup vs baseline: 7.6694x; 1.1220x over previous
//
#include <hip/hip_runtime.h>
#include <math.h>

typedef _Float16 f16;
typedef f16 f16x8 __attribute__((ext_vector_type(8)));
typedef float f32x16 __attribute__((ext_vector_type(16)));

static constexpr int Bn = 16;
static constexpr int Kn = 4096;
static constexpr int NPTS = Bn * Kn;    // 65536
static constexpr int MGRID = 512;       // qg8(16) x b(16) x dir(2)
static constexpr int NPSUM = 1024;      // old 1024-slot psum layout
static constexpr float WBIG = 49152.0f; // exact in fp16
static constexpr float QMIN0 = 3e37f;

// FINAL (R14 verbatim, best verified: 27.7 us). Structure: fused in-
// register fragment build (R11) + qt=8/512 blocks (R7) + XCD swizzle (R5)
// + VGPR-pinned MFMA dst (R14). The R5-R16 elimination matrix closed
// every other axis: traffic (R3/R7), TLP (R4/R8/R16), load ILP (R6/R15
// spill), acc depth (R9/R12), VALU count (R11), dispatch count (R11),
// ticket tails (R2/R10), MFMA halving (R13). Residual gap to the ~7 us
// MFMA floor is the per-t build->MFMA->drain chain at 2 waves/SIMD,
// which the allocator refuses to pipeline without spilling.
__global__ __launch_bounds__(256, 2) void chamfer_fused_kernel(
        const float* __restrict__ pred, const float* __restrict__ target,
        const int* __restrict__ mask,
        float* __restrict__ psum, unsigned int* __restrict__ cnt4) {
    int bid = blockIdx.x;
    int lin = (bid & 7) * 64 + (bid >> 3);    // XCD-contiguous logical id
    int qg8 = lin & 15; lin >>= 4;            // qg8(16) fastest, b(16), dir(2)
    int b   = lin & 15; lin >>= 4;
    int dir = lin;                            // 0: queries=pred, refs=target
    int j0 = dir * 512 + b * 32 + qg8 * 2;    // old logical psum slots
    int j1 = j0 + 1;

    const float* __restrict__ Araw = dir ? pred : target;  // refs
    const float* __restrict__ Braw = dir ? target : pred;  // queries

    int tid = threadIdx.x;
    int w = tid >> 6, l = tid & 63;
    int r = l & 31, g = l >> 5;

    __shared__ float comb[4][8][64];

    // opaque zero C-operand: runtime value IS 0, provenance hidden.
    float zf;
    asm volatile("v_mov_b32 %0, 0" : "=v"(zf));
    f32x16 cz;
    #pragma unroll
    for (int i = 0; i < 16; ++i) cz[i] = zf;

    const f16 one = (f16)1.0f, zero = (f16)0.0f;

    // ---- B fragments for this block's 8 query tiles (same bit-values as
    // old prep's B slots: B = {xh,xl,xh,yh,yl,yh,zh,zl | zh,1,1,whB,wlB,0,0,0})
    f16x8 bq[8];
    unsigned int bcnt[8];
    #pragma unroll
    for (int qt = 0; qt < 8; ++qt) {
        int idx = b * 4096 + (qg8 * 8 + qt) * 32 + r;
        bool valid = mask[idx] != 0;
        float x = Braw[idx * 3 + 0], y = Braw[idx * 3 + 1], z = Braw[idx * 3 + 2];
        if (!valid) { x = 0.0f; y = 0.0f; z = 0.0f; }
        float wv = fmaf(x, x, fmaf(y, y, z * z));
        f16 xh = (f16)x, yh = (f16)y, zh = (f16)z;
        f16 xl = (f16)(x - (float)xh), yl = (f16)(y - (float)yh), zl = (f16)(z - (float)zh);
        f16 whB, wlB;
        if (valid) { f16 wh = (f16)wv; whB = wh; wlB = (f16)(wv - (float)wh); }
        else       { whB = (f16)(-WBIG); wlB = zero; }
        f16x8 blo = {xh, xl, xh, yh, yl, yh, zh, zl};
        f16x8 bhi = {zh, one, one, whB, wlB, zero, zero, zero};
        bq[qt] = g ? bhi : blo;
        // lanes r and r+32 hold the same point -> popcll is 2x the count
        unsigned long long mb = __ballot(valid);
        bcnt[qt] = (unsigned int)__popcll(mb) >> 1;
    }
    // dir=0 blocks own cnt4 slots b*64 + qg8*4 + m (64 consecutive points
    // each = qt pair (2m,2m+1)) — same values as old prep's ballots.
    if (dir == 0 && w == 0 && l == 0) {
        #pragma unroll
        for (int m = 0; m < 4; ++m)
            cnt4[b * 64 + qg8 * 4 + m] = bcnt[2 * m] + bcnt[2 * m + 1];
    }

    float qA[8], qB[8];
    #pragma unroll
    for (int qt = 0; qt < 8; ++qt) { qA[qt] = QMIN0; qB[qt] = QMIN0; }

    // wave w covers ref tiles rt = w + 4t, t = 0..31 (R7's exact order).
    #pragma unroll 4
    for (int t = 0; t < 32; ++t) {
        int idxA = b * 4096 + (w + 4 * t) * 32 + r;
        bool valid = mask[idxA] != 0;
        float x = Araw[idxA * 3 + 0], y = Araw[idxA * 3 + 1], z = Araw[idxA * 3 + 2];
        if (!valid) { x = 0.0f; y = 0.0f; z = 0.0f; }
        // A slots (bit-identical to old prep):
        // A = {m2xh,m2xh,m2xl,m2yh,m2yh,m2yl,m2zh,m2zh | m2zl,whA,wlA,1,1,0,0,0}
        float wv = fmaf(x, x, fmaf(y, y, z * z));
        f16 xh = (f16)x, yh = (f16)y, zh = (f16)z;
        f16 xl = (f16)(x - (float)xh), yl = (f16)(y - (float)yh), zl = (f16)(z - (float)zh);
        f16 m2xh = (f16)(-2.0f * (float)xh), m2xl = (f16)(-2.0f * (float)xl);
        f16 m2yh = (f16)(-2.0f * (float)yh), m2yl = (f16)(-2.0f * (float)yl);
        f16 m2zh = (f16)(-2.0f * (float)zh), m2zl = (f16)(-2.0f * (float)zl);
        f16 whA, wlA;
        if (valid) { f16 wh = (f16)wv; whA = wh; wlA = (f16)(wv - (float)wh); }
        else       { whA = (f16)WBIG; wlA = zero; }
        f16x8 alo = {m2xh, m2xh, m2xl, m2yh, m2yh, m2yl, m2zh, m2zh};
        f16x8 ahi = {m2zl, whA, wlA, one, one, zero, zero, zero};
        f16x8 a = g ? ahi : alo;

        #pragma unroll
        for (int qt = 0; qt < 8; ++qt) {
            f32x16 d = __builtin_amdgcn_mfma_f32_32x32x16_f16(a, bq[qt], cz, 0, 0, 0);
            asm volatile("" : "+v"(d));   // pin MFMA dst to VGPRs (no AGPR reads)
            #pragma unroll
            for (int i = 0; i < 4; ++i) {
                qA[qt] = fminf(fminf(qA[qt], d[4 * i + 0]), d[4 * i + 1]);  // -> v_min3
                qB[qt] = fminf(fminf(qB[qt], d[4 * i + 2]), d[4 * i + 3]);  // -> v_min3
            }
        }
    }

    #pragma unroll
    for (int qt = 0; qt < 8; ++qt) comb[w][qt][l] = fminf(qA[qt], qB[qt]);
    __syncthreads();

    // Two independent reductions, each the EXACT old-block computation.
    float c0 = 0.0f, c1 = 0.0f;
    if (tid < 128) {
        int qt = tid >> 5, c = tid & 31;
        float m0 = QMIN0, m1 = QMIN0;
        #pragma unroll
        for (int ww = 0; ww < 4; ++ww)
            #pragma unroll
            for (int h = 0; h < 2; ++h) {
                m0 = fminf(m0, comb[ww][qt][h * 32 + c]);
                m1 = fminf(m1, comb[ww][qt + 4][h * 32 + c]);
            }
        // m < -1e4 marks an invalid query (w_q = -WBIG); contributes 0
        c0 = (m0 < -1e4f) ? 0.0f : sqrtf(fmaxf(m0, 1e-12f));
        c1 = (m1 < -1e4f) ? 0.0f : sqrtf(fmaxf(m1, 1e-12f));
    }
    for (int off = 32; off; off >>= 1) {
        c0 += __shfl_down(c0, off, 64);
        c1 += __shfl_down(c1, off, 64);
    }
    __shared__ float ps0[4], ps1[4];
    if ((tid & 63) == 0) { ps0[tid >> 6] = c0; ps1[tid >> 6] = c1; }
    __syncthreads();
    if (tid == 0) {
        psum[j0] = ps0[0] + ps0[1] + ps0[2] + ps0[3];
        psum[j1] = ps1[0] + ps1[1] + ps1[2] + ps1[3];
    }
}

__global__ __launch_bounds__(256) void final_kernel(
        const unsigned int* __restrict__ cnt4, const float* __restrict__ psum,
        float* __restrict__ out) {
    int t = threadIdx.x;
    unsigned int c = 0;
    float s = 0.0f;
    #pragma unroll
    for (int i = 0; i < 4; ++i) {
        c += cnt4[t + 256 * i];
        s += psum[t + 256 * i];
    }
    for (int off = 32; off; off >>= 1) {
        c += __shfl_down(c, off, 64);
        s += __shfl_down(s, off, 64);
    }
    __shared__ unsigned int cs[4];
    __shared__ float ss[4];
    if ((t & 63) == 0) { cs[t >> 6] = c; ss[t >> 6] = s; }
    __syncthreads();
    if (t == 0) {
        unsigned int C = cs[0] + cs[1] + cs[2] + cs[3];
        float S = ss[0] + ss[1] + ss[2] + ss[3];
        out[0] = S * 0.5f / ((float)C + 1e-8f);
    }
}

extern "C" void kernel_launch(void* const* d_in, const int* in_sizes, int n_in,
                              void* d_out, int out_size, void* d_ws, size_t ws_size,
                              hipStream_t stream) {
    const float* pred = (const float*)d_in[0];
    const float* target = (const float*)d_in[1];
    const int* mask = (const int*)d_in[2];
    float* out = (float*)d_out;

    // ws: [psum 4K | cnt4 4K]
    char* ws = (char*)d_ws;
    float* psum = (float*)ws;
    unsigned int* cnt4 = (unsigned int*)(ws + NPSUM * sizeof(float));

    chamfer_fused_kernel<<<MGRID, 256, 0, stream>>>(
        pred, target, mask, psum, cnt4);
    final_kernel<<<1, 256, 0, stream>>>(cnt4, psum, out);
}